// Round 3
// baseline (415.114 us; speedup 1.0000x reference)
//
#include <hip/hip_runtime.h>

#define TOKENS 8192
#define IN_F   4096
#define OUT_F  4096
#define BS     32
#define NBR    128
#define NBC    128
#define NBLK   8192

// ---- fast path geometry ----
#define TM     256
#define NTILE  (TOKENS / TM)          // 32
#define G      4                      // block-rows per WG
#define NRG    (NBR / G)              // 32 rowgroups
#define XCHUNK (TM * BS)              // 8192 ushorts = 16 KB per (tile, blockcol)

// ---- ws layout (bytes) ----
#define WS_TBL      0ull                                     // 128*128 int = 64 KB
#define WS_CNT      65536ull                                 // fallback CSR counts (512 B)
#define WS_ENT      66048ull                                 // fallback CSR entries (64 KB)
#define WS_X        131584ull                                // bf16 x chunks, 64 MB
#define WS_W        (WS_X + (size_t)TOKENS * IN_F * 2)       // bf16 weight blocks, 16.78 MB
#define WS_REQ      (WS_W + (size_t)NBLK * BS * BS * 2)

typedef __bf16 bf16x8 __attribute__((ext_vector_type(8)));
typedef float  f32x4  __attribute__((ext_vector_type(4)));

__device__ __forceinline__ unsigned short f2bf(float f) {
    unsigned u = __float_as_uint(f);
    u += 0x7fffu + ((u >> 16) & 1u);   // RNE; inputs are finite randoms
    return (unsigned short)(u >> 16);
}

// ---------------- table build (fast path) ----------------
__global__ __launch_bounds__(256) void init_tbl_kernel(int* __restrict__ tbl) {
    tbl[blockIdx.x * 256 + threadIdx.x] = -1;
}
__global__ __launch_bounds__(256) void scatter_tbl_kernel(
    const int* __restrict__ br, const int* __restrict__ bc, int* __restrict__ tbl) {
    int i = blockIdx.x * 256 + threadIdx.x;   // positions are unique -> deterministic
    tbl[br[i] * NBC + bc[i]] = i;
}

// x fp32 [8192][4096] -> bf16 chunks [(t*128+c)][256 rows][32 cols], linear.
// Coalesced: each thread reads 32B contiguous, writes 16B into one chunk.
__global__ __launch_bounds__(256) void conv_x_kernel(
    const float* __restrict__ x, unsigned short* __restrict__ wsx)
{
    int row  = blockIdx.x >> 1;
    int col8 = (blockIdx.x & 1) * 256 + threadIdx.x;   // 0..511 (units of 8 floats)
    const float4* src = reinterpret_cast<const float4*>(
        x + (size_t)row * IN_F + col8 * 8);
    float4 f0 = src[0], f1 = src[1];
    ushort4 a, b;
    a.x = f2bf(f0.x); a.y = f2bf(f0.y); a.z = f2bf(f0.z); a.w = f2bf(f0.w);
    b.x = f2bf(f1.x); b.y = f2bf(f1.y); b.z = f2bf(f1.z); b.w = f2bf(f1.w);
    int t = row >> 8, r = row & 255;
    int c = col8 >> 2;
    int q = (col8 & 3) * 8;
    unsigned short* dst = wsx + (size_t)(t * 128 + c) * XCHUNK + r * BS + q;
    *reinterpret_cast<ushort4*>(dst)     = a;
    *reinterpret_cast<ushort4*>(dst + 4) = b;
}

// weights fp32 -> bf16 blocks, linear layout.
__global__ __launch_bounds__(128) void conv_w_kernel(
    const float* __restrict__ wdata, unsigned short* __restrict__ wsw)
{
    int idx = blockIdx.x;
    int g = threadIdx.x;                  // 0..127, 8 floats each
    const float4* src = reinterpret_cast<const float4*>(
        wdata + (size_t)idx * 1024 + g * 8);
    float4 f0 = src[0], f1 = src[1];
    ushort4 a, b;
    a.x = f2bf(f0.x); a.y = f2bf(f0.y); a.z = f2bf(f0.z); a.w = f2bf(f0.w);
    b.x = f2bf(f1.x); b.y = f2bf(f1.y); b.z = f2bf(f1.z); b.w = f2bf(f1.w);
    unsigned short* dst = wsw + (size_t)idx * 1024 + g * 8;
    *reinterpret_cast<ushort4*>(dst)     = a;
    *reinterpret_cast<ushort4*>(dst + 4) = b;
}

// Fast GEMM: WG = 256-token tile x 4 block-rows. No LDS, no barriers —
// all MFMA fragments are contiguous 16B runs in ws, loaded straight to VGPRs.
__global__ __launch_bounds__(256, 2) void bsl_gemm3_kernel(
    const unsigned short* __restrict__ wsx,
    const unsigned short* __restrict__ wsw,
    const float* __restrict__ bias,
    const int*   __restrict__ tbl,
    float*       __restrict__ out)
{
    // XCD-aware bijective swizzle; within an XCD, rowgroups of one tile stay
    // consecutive so the tile's 2MB x-panel is L2-hot.
    int orig = blockIdx.x;                  // 0..1023
    int xcd  = orig & 7;
    int slot = orig >> 3;                   // 0..127
    int t  = ((slot >> 5) << 3) + xcd;      // 0..31
    int rg = slot & 31;
    int r0 = rg * G;

    const int tid  = threadIdx.x;
    const int lane = tid & 63;
    const int wv   = tid >> 6;

    f32x4 acc[G][4][2] = {};                // [g][mt][nt] = 128 VGPR

    // per-lane base inside a chunk: row = wv*64 + mt*16 + (lane&15), k-slice (lane>>4)*8
    const unsigned short* xc = wsx + (size_t)t * 128 * XCHUNK
        + (wv * 64 + (lane & 15)) * BS + (lane >> 4) * 8;
    const unsigned short* wlane = wsw + (lane & 15) * BS + (lane >> 4) * 8;
    const int* trow = tbl + r0 * NBC;

    for (int c = 0; c < NBC; ++c, xc += XCHUNK) {
        bf16x8 af0 = *reinterpret_cast<const bf16x8*>(xc);
        bf16x8 af1 = *reinterpret_cast<const bf16x8*>(xc + 512);
        bf16x8 af2 = *reinterpret_cast<const bf16x8*>(xc + 1024);
        bf16x8 af3 = *reinterpret_cast<const bf16x8*>(xc + 1536);
        #pragma unroll
        for (int g = 0; g < G; ++g) {
            int idx = trow[g * NBC + c];           // wave-uniform scalar
            if (idx >= 0) {
                const unsigned short* wb = wlane + (size_t)idx * 1024;
                bf16x8 b0 = *reinterpret_cast<const bf16x8*>(wb);
                bf16x8 b1 = *reinterpret_cast<const bf16x8*>(wb + 512);
                acc[g][0][0] = __builtin_amdgcn_mfma_f32_16x16x32_bf16(af0, b0, acc[g][0][0], 0, 0, 0);
                acc[g][0][1] = __builtin_amdgcn_mfma_f32_16x16x32_bf16(af0, b1, acc[g][0][1], 0, 0, 0);
                acc[g][1][0] = __builtin_amdgcn_mfma_f32_16x16x32_bf16(af1, b0, acc[g][1][0], 0, 0, 0);
                acc[g][1][1] = __builtin_amdgcn_mfma_f32_16x16x32_bf16(af1, b1, acc[g][1][1], 0, 0, 0);
                acc[g][2][0] = __builtin_amdgcn_mfma_f32_16x16x32_bf16(af2, b0, acc[g][2][0], 0, 0, 0);
                acc[g][2][1] = __builtin_amdgcn_mfma_f32_16x16x32_bf16(af2, b1, acc[g][2][1], 0, 0, 0);
                acc[g][3][0] = __builtin_amdgcn_mfma_f32_16x16x32_bf16(af3, b0, acc[g][3][0], 0, 0, 0);
                acc[g][3][1] = __builtin_amdgcn_mfma_f32_16x16x32_bf16(af3, b1, acc[g][3][1], 0, 0, 0);
            }
        }
    }

    // epilogue: + bias, fp32 store. C/D: col=lane&15, row=(lane>>4)*4+j
    #pragma unroll
    for (int g = 0; g < G; ++g) {
        float b0v = bias[(r0 + g) * BS + (lane & 15)];
        float b1v = bias[(r0 + g) * BS + 16 + (lane & 15)];
        #pragma unroll
        for (int mt = 0; mt < 4; ++mt) {
            #pragma unroll
            for (int nt = 0; nt < 2; ++nt) {
                float bb = nt ? b1v : b0v;
                #pragma unroll
                for (int j = 0; j < 4; ++j) {
                    int row = t * TM + wv * 64 + mt * 16 + (lane >> 4) * 4 + j;
                    int col = (r0 + g) * BS + nt * 16 + (lane & 15);
                    out[(size_t)row * OUT_F + col] = acc[g][mt][nt][j] + bb;
                }
            }
        }
    }
}

// ---------------- fallback path (round-1 kernel, used if ws too small) ----------------
#define FTM 128
#define XPAD 40

__global__ __launch_bounds__(64) void build_csr_kernel(
    const int* __restrict__ br, const int* __restrict__ bc,
    int* __restrict__ counts, int* __restrict__ entries)
{
    int r = blockIdx.x;
    int lane = threadIdx.x;
    int cnt = 0;
    for (int base = 0; base < NBLK; base += 64) {
        int i = base + lane;
        bool m = (br[i] == r);
        unsigned long long mask = __ballot(m);
        if (m) {
            int pos = __popcll(mask & ((1ull << lane) - 1ull));
            entries[r * NBC + cnt + pos] = (i << 7) | bc[i];
        }
        cnt += __popcll(mask);
    }
    if (lane == 0) counts[r] = cnt;
}

__global__ __launch_bounds__(256) void bsl_gemm_kernel(
    const float* __restrict__ x,
    const float* __restrict__ wdata,
    const float* __restrict__ bias,
    const int*   __restrict__ counts,
    const int*   __restrict__ entries,
    float*       __restrict__ out)
{
    __shared__ unsigned short sxf[2][FTM][XPAD];
    __shared__ unsigned short swf[2][BS][XPAD];

    const int r    = blockIdx.x;
    const int t0   = blockIdx.y * FTM;
    const int tid  = threadIdx.x;
    const int lane = tid & 63;
    const int wv   = tid >> 6;

    const int cnt = counts[r];
    const int* rowent = entries + r * NBC;

    f32x4 acc[2][2] = {};
    float4 xr[4];
    float4 wr;

    const int xrow  = tid >> 3;
    const int xcol4 = tid & 7;

    auto loadX = [&](int c) {
        #pragma unroll
        for (int p = 0; p < 4; p++) {
            int row = p * 32 + xrow;
            xr[p] = *reinterpret_cast<const float4*>(
                &x[(size_t)(t0 + row) * IN_F + c * BS + xcol4 * 4]);
        }
    };
    auto loadW = [&](int idx) {
        wr = *reinterpret_cast<const float4*>(
            &wdata[(size_t)idx * BS * BS + xrow * BS + xcol4 * 4]);
    };
    auto writeX = [&](int b) {
        #pragma unroll
        for (int p = 0; p < 4; p++) {
            int row = p * 32 + xrow;
            ushort4 u;
            u.x = f2bf(xr[p].x); u.y = f2bf(xr[p].y);
            u.z = f2bf(xr[p].z); u.w = f2bf(xr[p].w);
            *reinterpret_cast<ushort4*>(&sxf[b][row][xcol4 * 4]) = u;
        }
    };
    auto writeW = [&](int b) {
        ushort4 u;
        u.x = f2bf(wr.x); u.y = f2bf(wr.y);
        u.z = f2bf(wr.z); u.w = f2bf(wr.w);
        *reinterpret_cast<ushort4*>(&swf[b][xrow][xcol4 * 4]) = u;
    };
    auto computeF = [&](int b) {
        bf16x8 af[2], bfr[2];
        #pragma unroll
        for (int mt = 0; mt < 2; mt++) {
            int row = wv * 32 + mt * 16 + (lane & 15);
            af[mt] = *reinterpret_cast<const bf16x8*>(&sxf[b][row][(lane >> 4) * 8]);
        }
        #pragma unroll
        for (int nt = 0; nt < 2; nt++) {
            int row = nt * 16 + (lane & 15);
            bfr[nt] = *reinterpret_cast<const bf16x8*>(&swf[b][row][(lane >> 4) * 8]);
        }
        #pragma unroll
        for (int mt = 0; mt < 2; mt++)
            #pragma unroll
            for (int nt = 0; nt < 2; nt++)
                acc[mt][nt] = __builtin_amdgcn_mfma_f32_16x16x32_bf16(
                    af[mt], bfr[nt], acc[mt][nt], 0, 0, 0);
    };

    if (cnt > 0) {
        int e0 = rowent[0];
        loadX(e0 & 127); loadW(e0 >> 7);
        writeX(0); writeW(0);
        __syncthreads();
        for (int k = 0; k < cnt; k++) {
            int cur = k & 1;
            bool pref = (k + 1 < cnt);
            if (pref) {
                int e = rowent[k + 1];
                loadX(e & 127); loadW(e >> 7);
            }
            computeF(cur);
            if (pref) { writeX(cur ^ 1); writeW(cur ^ 1); }
            __syncthreads();
        }
    }

    float b0 = bias[r * BS + (lane & 15)];
    float b1 = bias[r * BS + 16 + (lane & 15)];
    #pragma unroll
    for (int mt = 0; mt < 2; mt++) {
        #pragma unroll
        for (int nt = 0; nt < 2; nt++) {
            float bb = nt ? b1 : b0;
            #pragma unroll
            for (int j = 0; j < 4; j++) {
                int row = t0 + wv * 32 + mt * 16 + (lane >> 4) * 4 + j;
                int col = r * BS + nt * 16 + (lane & 15);
                out[(size_t)row * OUT_F + col] = acc[mt][nt][j] + bb;
            }
        }
    }
}

extern "C" void kernel_launch(void* const* d_in, const int* in_sizes, int n_in,
                              void* d_out, int out_size, void* d_ws, size_t ws_size,
                              hipStream_t stream)
{
    const float* x     = (const float*)d_in[0];
    const float* wdata = (const float*)d_in[1];
    const float* bias  = (const float*)d_in[2];
    const int*   br    = (const int*)d_in[3];
    const int*   bc    = (const int*)d_in[4];
    float* out = (float*)d_out;

    if (ws_size >= WS_REQ) {
        int* tbl = (int*)((char*)d_ws + WS_TBL);
        unsigned short* wsx = (unsigned short*)((char*)d_ws + WS_X);
        unsigned short* wsw = (unsigned short*)((char*)d_ws + WS_W);
        init_tbl_kernel<<<NBR * NBC / 256, 256, 0, stream>>>(tbl);
        scatter_tbl_kernel<<<NBLK / 256, 256, 0, stream>>>(br, bc, tbl);
        conv_x_kernel<<<TOKENS * 2, 256, 0, stream>>>(x, wsx);
        conv_w_kernel<<<NBLK, 128, 0, stream>>>(wdata, wsw);
        bsl_gemm3_kernel<<<NTILE * NRG, 256, 0, stream>>>(
            wsx, wsw, bias, tbl, out);
    } else {
        int* counts  = (int*)((char*)d_ws + WS_CNT);
        int* entries = (int*)((char*)d_ws + WS_ENT);
        build_csr_kernel<<<NBR, 64, 0, stream>>>(br, bc, counts, entries);
        bsl_gemm_kernel<<<dim3(NBR, TOKENS / FTM), 256, 0, stream>>>(
            x, wdata, bias, counts, entries, out);
    }
}

// Round 4
// 253.478 us; speedup vs baseline: 1.6377x; 1.6377x over previous
//
#include <hip/hip_runtime.h>

#define TOKENS 8192
#define IN_F   4096
#define OUT_F  4096
#define BS     32
#define NBR    128
#define NBC    128
#define NBLK   8192

// ---- fast path geometry ----
#define TM     128                    // token rows per WG
#define NTILE  (TOKENS / TM)          // 64
#define G      8                      // block-rows per WG
#define NRG    (NBR / G)              // 16 rowgroups
#define XCHUNK (TM * BS)              // 4096 ushorts = 8 KB per (tile, blockcol)

// ---- ws layout (bytes) ----
#define WS_TBL      0ull                                     // 16*128*8 int = 64 KB
#define WS_CNT      65536ull                                 // fallback CSR counts
#define WS_ENT      66048ull                                 // fallback CSR entries
#define WS_X        131584ull                                // bf16 x chunks, 64 MB
#define WS_W        (WS_X + (size_t)TOKENS * IN_F * 2)       // bf16 blocks, 16.78 MB
#define WS_REQ      (WS_W + (size_t)NBLK * BS * BS * 2)

typedef __bf16 bf16x8 __attribute__((ext_vector_type(8)));
typedef float  f32x4  __attribute__((ext_vector_type(4)));

#define GLDS16(gp, lp) __builtin_amdgcn_global_load_lds( \
    (const __attribute__((address_space(1))) unsigned int*)(gp), \
    (__attribute__((address_space(3))) unsigned int*)(lp), 16, 0, 0)

__device__ __forceinline__ unsigned short f2bf(float f) {
    unsigned u = __float_as_uint(f);
    u += 0x7fffu + ((u >> 16) & 1u);   // RNE; inputs are finite randoms
    return (unsigned short)(u >> 16);
}

// ---------------- index table: tbl2[rg][c][8] = block idx or -1 ----------------
__global__ __launch_bounds__(256) void init_tbl_kernel(int* __restrict__ tbl) {
    tbl[blockIdx.x * 256 + threadIdx.x] = -1;
}
__global__ __launch_bounds__(256) void scatter_tbl_kernel(
    const int* __restrict__ br, const int* __restrict__ bc, int* __restrict__ tbl) {
    int i = blockIdx.x * 256 + threadIdx.x;   // positions unique -> deterministic
    int r = br[i], c = bc[i];
    tbl[(r >> 3) * (NBC * G) + c * G + (r & 7)] = i;
}

// x fp32 -> bf16 chunks [(t*128+c)][128 rows][32 cols] with baked XOR swizzle:
// element (r,q) at r*32 + ((q>>3) ^ ((r>>1)&3))*8 + (q&7)
__global__ __launch_bounds__(256) void conv_x_kernel(
    const float* __restrict__ x, unsigned short* __restrict__ wsx)
{
    int row  = blockIdx.x >> 1;
    int col8 = (blockIdx.x & 1) * 256 + threadIdx.x;   // units of 8 floats
    const float4* src = reinterpret_cast<const float4*>(
        x + (size_t)row * IN_F + col8 * 8);
    float4 f0 = src[0], f1 = src[1];
    ushort4 a, b;
    a.x = f2bf(f0.x); a.y = f2bf(f0.y); a.z = f2bf(f0.z); a.w = f2bf(f0.w);
    b.x = f2bf(f1.x); b.y = f2bf(f1.y); b.z = f2bf(f1.z); b.w = f2bf(f1.w);
    int t = row >> 7, r = row & 127;
    int c = col8 >> 2, q8 = col8 & 3;
    int sw = (r >> 1) & 3;
    unsigned short* dst = wsx + (size_t)(t * NBC + c) * XCHUNK + r * BS + ((q8 ^ sw) * 8);
    *reinterpret_cast<ushort4*>(dst)     = a;
    *reinterpret_cast<ushort4*>(dst + 4) = b;
}

// weights fp32 -> bf16 blocks with the same baked swizzle.
__global__ __launch_bounds__(128) void conv_w_kernel(
    const float* __restrict__ wdata, unsigned short* __restrict__ wsw)
{
    int idx = blockIdx.x;
    int g = threadIdx.x;                  // 0..127, 8 floats each
    int r = g >> 2, k = g & 3;
    const float4* src = reinterpret_cast<const float4*>(
        wdata + (size_t)idx * 1024 + r * 32 + k * 8);
    float4 f0 = src[0], f1 = src[1];
    ushort4 a, b;
    a.x = f2bf(f0.x); a.y = f2bf(f0.y); a.z = f2bf(f0.z); a.w = f2bf(f0.w);
    b.x = f2bf(f1.x); b.y = f2bf(f1.y); b.z = f2bf(f1.z); b.w = f2bf(f1.w);
    unsigned short* dst = wsw + (size_t)idx * 1024 + r * 32 + ((k ^ ((r >> 1) & 3)) * 8);
    *reinterpret_cast<ushort4*>(dst)     = a;
    *reinterpret_cast<ushort4*>(dst + 4) = b;
}

// GEMM: WG = 128-token tile x 8 block-rows, 512 threads, double-buffered glds.
__global__ __launch_bounds__(512, 4) void bsl_gemm4_kernel(
    const unsigned short* __restrict__ wsx,
    const unsigned short* __restrict__ wsw,
    const float* __restrict__ bias,
    const int*   __restrict__ tbl,
    float*       __restrict__ out)
{
    __shared__ unsigned short sx[2][XCHUNK];      // 2 x 8 KB
    __shared__ unsigned short swt[2][G * 1024];   // 2 x 16 KB

    // XCD-aware bijective swizzle: each XCD owns 8 consecutive tiles;
    // within an XCD, rowgroups of one tile are consecutive (x panel L2-hot).
    int orig = blockIdx.x;                  // 0..1023
    int xcd  = orig & 7;
    int slot = orig >> 3;                   // 0..127
    int t  = xcd * 8 + (slot >> 4);         // 0..63
    int rg = slot & 15;

    const int tid  = threadIdx.x;
    const int lane = tid & 63;
    const int wv   = tid >> 6;              // 0..7
    const int swl  = ((lane >> 4) ^ ((lane >> 1) & 3)) * 8;

    f32x4 acc[G][2] = {};                   // 64 VGPR

    const char* xbase = (const char*)(wsx + (size_t)t * NBC * XCHUNK);
    const int*  trow  = tbl + rg * (NBC * G);
    const int   xoff  = wv * 1024 + lane * 16;   // byte offset within 8 KB chunk

    auto stage = [&](int c, int buf) {
        GLDS16(xbase + (size_t)c * (XCHUNK * 2) + xoff, (char*)(&sx[buf][0]) + xoff);
        int idxw = trow[c * G + wv];        // wave-uniform s_load
        if (idxw >= 0) {
            const char* wsrc = (const char*)(wsw + (size_t)idxw * 1024);
            char* wdst = (char*)(&swt[buf][0]) + wv * 2048;
            GLDS16(wsrc + lane * 16,        wdst + lane * 16);
            GLDS16(wsrc + 1024 + lane * 16, wdst + 1024 + lane * 16);
        }
    };

    auto compute = [&](int buf, int4 ia, int4 ib) {
        const unsigned short* xb = &sx[buf][0];
        const unsigned short* wb = &swt[buf][0];
        bf16x8 af = *reinterpret_cast<const bf16x8*>(
            &xb[(wv * 16 + (lane & 15)) * BS + swl]);
        #define DO_G(g, cond) if ((cond) >= 0) { \
            const unsigned short* wp = &wb[(g) * 1024 + (lane & 15) * BS + swl]; \
            bf16x8 b0 = *reinterpret_cast<const bf16x8*>(wp); \
            bf16x8 b1 = *reinterpret_cast<const bf16x8*>(wp + 512); \
            acc[g][0] = __builtin_amdgcn_mfma_f32_16x16x32_bf16(af, b0, acc[g][0], 0, 0, 0); \
            acc[g][1] = __builtin_amdgcn_mfma_f32_16x16x32_bf16(af, b1, acc[g][1], 0, 0, 0); }
        DO_G(0, ia.x) DO_G(1, ia.y) DO_G(2, ia.z) DO_G(3, ia.w)
        DO_G(4, ib.x) DO_G(5, ib.y) DO_G(6, ib.z) DO_G(7, ib.w)
        #undef DO_G
    };

    int4 ia = *reinterpret_cast<const int4*>(&trow[0]);
    int4 ib = *reinterpret_cast<const int4*>(&trow[4]);
    stage(0, 0);
    __syncthreads();
    int buf = 0;
    for (int c = 0; c < NBC - 1; ++c) {
        int4 na = *reinterpret_cast<const int4*>(&trow[(c + 1) * G]);
        int4 nb = *reinterpret_cast<const int4*>(&trow[(c + 1) * G + 4]);
        stage(c + 1, buf ^ 1);
        compute(buf, ia, ib);
        __syncthreads();
        ia = na; ib = nb; buf ^= 1;
    }
    compute(buf, ia, ib);

    // epilogue: + bias, fp32 store. C/D: col=lane&15, row=(lane>>4)*4+j
    #pragma unroll
    for (int g = 0; g < G; ++g) {
        #pragma unroll
        for (int nt = 0; nt < 2; ++nt) {
            int col = (rg * G + g) * BS + nt * 16 + (lane & 15);
            float bb = bias[col];
            #pragma unroll
            for (int j = 0; j < 4; ++j) {
                int row = t * TM + wv * 16 + (lane >> 4) * 4 + j;
                out[(size_t)row * OUT_F + col] = acc[g][nt][j] + bb;
            }
        }
    }
}

// ---------------- fallback path (round-1 kernel, used if ws too small) ----------------
#define FTM 128
#define XPAD 40

__global__ __launch_bounds__(64) void build_csr_kernel(
    const int* __restrict__ br, const int* __restrict__ bc,
    int* __restrict__ counts, int* __restrict__ entries)
{
    int r = blockIdx.x;
    int lane = threadIdx.x;
    int cnt = 0;
    for (int base = 0; base < NBLK; base += 64) {
        int i = base + lane;
        bool m = (br[i] == r);
        unsigned long long mask = __ballot(m);
        if (m) {
            int pos = __popcll(mask & ((1ull << lane) - 1ull));
            entries[r * NBC + cnt + pos] = (i << 7) | bc[i];
        }
        cnt += __popcll(mask);
    }
    if (lane == 0) counts[r] = cnt;
}

__global__ __launch_bounds__(256) void bsl_gemm_kernel(
    const float* __restrict__ x,
    const float* __restrict__ wdata,
    const float* __restrict__ bias,
    const int*   __restrict__ counts,
    const int*   __restrict__ entries,
    float*       __restrict__ out)
{
    __shared__ unsigned short sxf[2][FTM][XPAD];
    __shared__ unsigned short swf[2][BS][XPAD];

    const int r    = blockIdx.x;
    const int t0   = blockIdx.y * FTM;
    const int tid  = threadIdx.x;
    const int lane = tid & 63;
    const int wv   = tid >> 6;

    const int cnt = counts[r];
    const int* rowent = entries + r * NBC;

    f32x4 acc[2][2] = {};
    float4 xr[4];
    float4 wr;

    const int xrow  = tid >> 3;
    const int xcol4 = tid & 7;

    auto loadX = [&](int c) {
        #pragma unroll
        for (int p = 0; p < 4; p++) {
            int row = p * 32 + xrow;
            xr[p] = *reinterpret_cast<const float4*>(
                &x[(size_t)(t0 + row) * IN_F + c * BS + xcol4 * 4]);
        }
    };
    auto loadW = [&](int idx) {
        wr = *reinterpret_cast<const float4*>(
            &wdata[(size_t)idx * BS * BS + xrow * BS + xcol4 * 4]);
    };
    auto writeX = [&](int b) {
        #pragma unroll
        for (int p = 0; p < 4; p++) {
            int row = p * 32 + xrow;
            ushort4 u;
            u.x = f2bf(xr[p].x); u.y = f2bf(xr[p].y);
            u.z = f2bf(xr[p].z); u.w = f2bf(xr[p].w);
            *reinterpret_cast<ushort4*>(&sxf[b][row][xcol4 * 4]) = u;
        }
    };
    auto writeW = [&](int b) {
        ushort4 u;
        u.x = f2bf(wr.x); u.y = f2bf(wr.y);
        u.z = f2bf(wr.z); u.w = f2bf(wr.w);
        *reinterpret_cast<ushort4*>(&swf[b][xrow][xcol4 * 4]) = u;
    };
    auto computeF = [&](int b) {
        bf16x8 af[2], bfr[2];
        #pragma unroll
        for (int mt = 0; mt < 2; mt++) {
            int row = wv * 32 + mt * 16 + (lane & 15);
            af[mt] = *reinterpret_cast<const bf16x8*>(&sxf[b][row][(lane >> 4) * 8]);
        }
        #pragma unroll
        for (int nt = 0; nt < 2; nt++) {
            int row = nt * 16 + (lane & 15);
            bfr[nt] = *reinterpret_cast<const bf16x8*>(&swf[b][row][(lane >> 4) * 8]);
        }
        #pragma unroll
        for (int mt = 0; mt < 2; mt++)
            #pragma unroll
            for (int nt = 0; nt < 2; nt++)
                acc[mt][nt] = __builtin_amdgcn_mfma_f32_16x16x32_bf16(
                    af[mt], bfr[nt], acc[mt][nt], 0, 0, 0);
    };

    if (cnt > 0) {
        int e0 = rowent[0];
        loadX(e0 & 127); loadW(e0 >> 7);
        writeX(0); writeW(0);
        __syncthreads();
        for (int k = 0; k < cnt; k++) {
            int cur = k & 1;
            bool pref = (k + 1 < cnt);
            if (pref) {
                int e = rowent[k + 1];
                loadX(e & 127); loadW(e >> 7);
            }
            computeF(cur);
            if (pref) { writeX(cur ^ 1); writeW(cur ^ 1); }
            __syncthreads();
        }
    }

    float b0 = bias[r * BS + (lane & 15)];
    float b1 = bias[r * BS + 16 + (lane & 15)];
    #pragma unroll
    for (int mt = 0; mt < 2; mt++) {
        #pragma unroll
        for (int nt = 0; nt < 2; nt++) {
            float bb = nt ? b1 : b0;
            #pragma unroll
            for (int j = 0; j < 4; j++) {
                int row = t0 + wv * 32 + mt * 16 + (lane >> 4) * 4 + j;
                int col = r * BS + nt * 16 + (lane & 15);
                out[(size_t)row * OUT_F + col] = acc[mt][nt][j] + bb;
            }
        }
    }
}

extern "C" void kernel_launch(void* const* d_in, const int* in_sizes, int n_in,
                              void* d_out, int out_size, void* d_ws, size_t ws_size,
                              hipStream_t stream)
{
    const float* x     = (const float*)d_in[0];
    const float* wdata = (const float*)d_in[1];
    const float* bias  = (const float*)d_in[2];
    const int*   br    = (const int*)d_in[3];
    const int*   bc    = (const int*)d_in[4];
    float* out = (float*)d_out;

    if (ws_size >= WS_REQ) {
        int* tbl = (int*)((char*)d_ws + WS_TBL);
        unsigned short* wsx = (unsigned short*)((char*)d_ws + WS_X);
        unsigned short* wsw = (unsigned short*)((char*)d_ws + WS_W);
        init_tbl_kernel<<<NRG * NBC * G / 256, 256, 0, stream>>>(tbl);
        scatter_tbl_kernel<<<NBLK / 256, 256, 0, stream>>>(br, bc, tbl);
        conv_x_kernel<<<TOKENS * 2, 256, 0, stream>>>(x, wsx);
        conv_w_kernel<<<NBLK, 128, 0, stream>>>(wdata, wsw);
        bsl_gemm4_kernel<<<NTILE * NRG, 512, 0, stream>>>(
            wsx, wsw, bias, tbl, out);
    } else {
        int* counts  = (int*)((char*)d_ws + WS_CNT);
        int* entries = (int*)((char*)d_ws + WS_ENT);
        build_csr_kernel<<<NBR, 64, 0, stream>>>(br, bc, counts, entries);
        bsl_gemm_kernel<<<dim3(NBR, TOKENS / FTM), 256, 0, stream>>>(
            x, wdata, bias, counts, entries, out);
    }
}